// Round 1
// baseline (559.305 us; speedup 1.0000x reference)
//
#include <hip/hip_runtime.h>

typedef __attribute__((ext_vector_type(4))) float float4_t;
typedef __attribute__((ext_vector_type(8))) short short8_t;
typedef __attribute__((ext_vector_type(4))) unsigned short ushort4_t;

#define B_ 8
#define S_ 14
#define P_ 196      // S*S
#define N_ 1568     // B*P
#define D_ 2048
#define C_ 20
#define WD_ 300
#define I_ 1024

__device__ __forceinline__ unsigned short f2bf(float f) {
    unsigned u = __builtin_bit_cast(unsigned, f);
    u += 0x7FFFu + ((u >> 16) & 1u);   // round-to-nearest-even
    return (unsigned short)(u >> 16);
}

// ---------------- fp32 -> bf16 conversion (vectorized x4) ----------------
__global__ void cvt_bf16_kernel(const float* __restrict__ src, unsigned short* __restrict__ dst) {
    int i4 = blockIdx.x * blockDim.x + threadIdx.x;
    float4_t v = ((const float4_t*)src)[i4];
    ushort4_t o;
    o.x = f2bf(v.x); o.y = f2bf(v.y); o.z = f2bf(v.z); o.w = f2bf(v.w);
    ((ushort4_t*)dst)[i4] = o;
}

// ---------------- h_word[c,i] = sum_k wf[c,k] * W2[i,k] ----------------
__global__ void hword_kernel(const float* __restrict__ wf, const float* __restrict__ W2,
                             float* __restrict__ hw) {
    int idx = blockIdx.x * blockDim.x + threadIdx.x;   // 0..20479
    int c = idx >> 10, i = idx & 1023;
    const float* wr  = wf + c * WD_;
    const float* w2r = W2 + i * WD_;
    float s = 0.f;
    #pragma unroll 4
    for (int k = 0; k < WD_; k++) s += wr[k] * w2r[k];
    hw[idx] = s;
}

// ---------------- w_eff[i] = sum_j W4[j] * W3[j,i] ----------------
__global__ void weff_kernel(const float* __restrict__ W4, const float* __restrict__ W3,
                            float* __restrict__ we) {
    int i = blockIdx.x * blockDim.x + threadIdx.x;     // 0..1023
    float s = 0.f;
    #pragma unroll 4
    for (int j = 0; j < I_; j++) s += W4[j] * W3[j * I_ + i];
    we[i] = s;
}

// ---------------- bias = dot(b3, W4) + b4[0] ----------------
__global__ void bias_kernel(const float* __restrict__ b3, const float* __restrict__ W4,
                            const float* __restrict__ b4, float* __restrict__ bias) {
    __shared__ float r[256];
    int tid = threadIdx.x;
    float s = 0.f;
    for (int j = tid; j < I_; j += 256) s += b3[j] * W4[j];
    r[tid] = s;
    __syncthreads();
    for (int o = 128; o > 0; o >>= 1) {
        if (tid < o) r[tid] += r[tid + o];
        __syncthreads();
    }
    if (tid == 0) bias[0] = r[0] + b4[0];
}

// ---------------- h_img = X @ W1^T via bf16 MFMA 16x16x32 ----------------
// wave computes 32(m) x 64(n) block: 2x4 tiles of 16x16. 49*16 = 784 waves = 196 blocks.
__global__ __launch_bounds__(256) void gemm_himg_kernel(const unsigned short* __restrict__ Xb,
                                                        const unsigned short* __restrict__ W1b,
                                                        float* __restrict__ H) {
    int wave = blockIdx.x * 4 + (threadIdx.x >> 6);
    int lane = threadIdx.x & 63;
    int mjob = wave >> 4;       // 0..48
    int njob = wave & 15;       // 0..15
    int m0 = mjob * 32, n0 = njob * 64;
    int ra = lane & 15;
    int kq = (lane >> 4) * 8;

    float4_t acc[2][4] = {};
    const unsigned short* xa = Xb  + (size_t)(m0 + ra) * D_ + kq;
    const unsigned short* wb = W1b + (size_t)(n0 + ra) * D_ + kq;

    for (int k0 = 0; k0 < D_; k0 += 32) {
        short8_t a0 = *(const short8_t*)(xa + k0);
        short8_t a1 = *(const short8_t*)(xa + 16 * D_ + k0);
        short8_t b0 = *(const short8_t*)(wb + k0);
        short8_t b1 = *(const short8_t*)(wb + 16 * D_ + k0);
        short8_t b2 = *(const short8_t*)(wb + 32 * D_ + k0);
        short8_t b3v = *(const short8_t*)(wb + 48 * D_ + k0);
        acc[0][0] = __builtin_amdgcn_mfma_f32_16x16x32_bf16(a0, b0, acc[0][0], 0, 0, 0);
        acc[0][1] = __builtin_amdgcn_mfma_f32_16x16x32_bf16(a0, b1, acc[0][1], 0, 0, 0);
        acc[0][2] = __builtin_amdgcn_mfma_f32_16x16x32_bf16(a0, b2, acc[0][2], 0, 0, 0);
        acc[0][3] = __builtin_amdgcn_mfma_f32_16x16x32_bf16(a0, b3v, acc[0][3], 0, 0, 0);
        acc[1][0] = __builtin_amdgcn_mfma_f32_16x16x32_bf16(a1, b0, acc[1][0], 0, 0, 0);
        acc[1][1] = __builtin_amdgcn_mfma_f32_16x16x32_bf16(a1, b1, acc[1][1], 0, 0, 0);
        acc[1][2] = __builtin_amdgcn_mfma_f32_16x16x32_bf16(a1, b2, acc[1][2], 0, 0, 0);
        acc[1][3] = __builtin_amdgcn_mfma_f32_16x16x32_bf16(a1, b3v, acc[1][3], 0, 0, 0);
    }

    int col = lane & 15, rq = (lane >> 4) * 4;
    #pragma unroll
    for (int mt = 0; mt < 2; mt++) {
        #pragma unroll
        for (int nt = 0; nt < 4; nt++) {
            float4_t v = acc[mt][nt];
            int rbase = m0 + mt * 16 + rq;
            int cidx = n0 + nt * 16 + col;
            H[(rbase + 0) * I_ + cidx] = v.x;
            H[(rbase + 1) * I_ + cidx] = v.y;
            H[(rbase + 2) * I_ + cidx] = v.z;
            H[(rbase + 3) * I_ + cidx] = v.w;
        }
    }
}

// ---------------- logits[n,c] = sum_i tanh(h_img[n,i]*h_word[c,i])*w_eff[i] + bias ----------------
__global__ __launch_bounds__(256) void logits_kernel(const float* __restrict__ H,
                                                     const float* __restrict__ hw,
                                                     const float* __restrict__ we,
                                                     const float* __restrict__ bias,
                                                     float* __restrict__ lg) {
    __shared__ float sh[I_];
    __shared__ float sw[I_];
    int n = blockIdx.x, tid = threadIdx.x;
    #pragma unroll
    for (int t = 0; t < 4; t++) {
        sh[tid + 256 * t] = H[(size_t)n * I_ + tid + 256 * t];
        sw[tid + 256 * t] = we[tid + 256 * t];
    }
    __syncthreads();
    int wv = tid >> 6, lane = tid & 63;
    float bz = bias[0];
    for (int j = 0; j < 5; j++) {
        int c = j * 4 + wv;
        const float* hwc = hw + c * I_;
        float s = 0.f;
        #pragma unroll 4
        for (int i = lane; i < I_; i += 64) {
            float x = sh[i] * hwc[i];
            float e = __expf(2.f * x);
            float th = 1.f - __fdividef(2.f, e + 1.f);
            s += th * sw[i];
        }
        #pragma unroll
        for (int o = 32; o > 0; o >>= 1) s += __shfl_down(s, o);
        if (lane == 0) lg[n * C_ + c] = s + bz;
    }
}

// ---------------- softmax over 196 positions per (b,c); write coef output ----------------
__global__ __launch_bounds__(256) void softmax_kernel(const float* __restrict__ lg,
                                                      float* __restrict__ coef) {
    __shared__ float r[4];
    __shared__ float bval;
    int bx = blockIdx.x;
    int b = bx / C_, c = bx % C_;
    int tid = threadIdx.x, wv = tid >> 6, lane = tid & 63;
    float v = (tid < P_) ? lg[(b * P_ + tid) * C_ + c] : -3.0e38f;
    float m = v;
    #pragma unroll
    for (int o = 32; o > 0; o >>= 1) m = fmaxf(m, __shfl_down(m, o));
    if (lane == 0) r[wv] = m;
    __syncthreads();
    if (tid == 0) bval = fmaxf(fmaxf(r[0], r[1]), fmaxf(r[2], r[3]));
    __syncthreads();
    float mx = bval;
    float e = (tid < P_) ? __expf(v - mx) : 0.f;
    float s = e;
    #pragma unroll
    for (int o = 32; o > 0; o >>= 1) s += __shfl_down(s, o);
    __syncthreads();
    if (lane == 0) r[wv] = s;
    __syncthreads();
    if (tid == 0) bval = r[0] + r[1] + r[2] + r[3];
    __syncthreads();
    if (tid < P_) coef[(b * P_ + tid) * C_ + c] = e / bval;
}

// ---------------- fmwc[b,p,c,d] = img[b,p,d] * coef[b,p,c] ----------------
__global__ __launch_bounds__(256) void fmwc_kernel(const float* __restrict__ img,
                                                   const float* __restrict__ coef,
                                                   float* __restrict__ fm) {
    __shared__ float sc[C_];
    int bp = blockIdx.x, tid = threadIdx.x;
    if (tid < C_) sc[tid] = coef[bp * C_ + tid];
    __syncthreads();
    const float4_t* ir = (const float4_t*)(img + (size_t)bp * D_);
    float4_t v0 = ir[tid], v1 = ir[tid + 256];
    float4_t* ob = (float4_t*)(fm + (size_t)bp * C_ * D_);
    #pragma unroll
    for (int c = 0; c < C_; c++) {
        float s = sc[c];
        ob[c * 512 + tid] = v0 * s;
        ob[c * 512 + tid + 256] = v1 * s;
    }
}

// ---------------- semantic[b,c,d] = sum_p img[b,p,d]*coef[b,p,c] ----------------
// grid: B*C*4 (d split in 4 chunks of 512), 128 threads x float4
__global__ __launch_bounds__(128) void semantic_kernel(const float* __restrict__ img,
                                                       const float* __restrict__ coef,
                                                       float* __restrict__ sem) {
    __shared__ float sc[P_];
    int bx = blockIdx.x;
    int b = bx / 80;
    int rem = bx % 80;
    int c = rem >> 2, ch = rem & 3;
    int tid = threadIdx.x;
    for (int q = tid; q < P_; q += 128) sc[q] = coef[(b * P_ + q) * C_ + c];
    __syncthreads();
    const float4_t* base = (const float4_t*)(img + (size_t)b * P_ * D_) + ch * 128 + tid;
    float4_t acc = {0.f, 0.f, 0.f, 0.f};
    #pragma unroll 4
    for (int p = 0; p < P_; p++) {
        acc += base[p * 512] * sc[p];
    }
    ((float4_t*)(sem + (size_t)(b * C_ + c) * D_))[ch * 128 + tid] = acc;
}

extern "C" void kernel_launch(void* const* d_in, const int* in_sizes, int n_in,
                              void* d_out, int out_size, void* d_ws, size_t ws_size,
                              hipStream_t stream) {
    const float* img = (const float*)d_in[0];
    const float* wf  = (const float*)d_in[1];
    const float* W1  = (const float*)d_in[2];
    const float* W2  = (const float*)d_in[3];
    const float* W3  = (const float*)d_in[4];
    const float* b3  = (const float*)d_in[5];
    const float* W4  = (const float*)d_in[6];
    const float* b4  = (const float*)d_in[7];

    float* out  = (float*)d_out;
    float* sem  = out;                                  // [B,C,D]      = 327680
    float* fm   = out + (size_t)B_ * C_ * D_;           // [B,S,S,C,D]  = 64225280
    float* coef = fm + (size_t)N_ * C_ * D_;            // [B,S,S,C]    = 31360

    char* ws = (char*)d_ws;
    unsigned short* Xb  = (unsigned short*)ws;                  // 1568*2048*2  = 6,422,528 B
    unsigned short* W1b = (unsigned short*)(ws + 6422528);      // 1024*2048*2  = 4,194,304 B
    float* H    = (float*)(ws + 10616832);                      // 1568*1024*4  = 6,422,528 B
    float* hw   = (float*)(ws + 17039360);                      // 20*1024*4    = 81,920 B
    float* we   = (float*)(ws + 17121280);                      // 1024*4       = 4,096 B
    float* bias = (float*)(ws + 17125376);                      // 256 B
    float* lg   = (float*)(ws + 17125632);                      // 1568*20*4    = 125,440 B

    cvt_bf16_kernel<<<3136, 256, 0, stream>>>(img, Xb);     // 1568*2048 /4/256
    cvt_bf16_kernel<<<2048, 256, 0, stream>>>(W1, W1b);     // 1024*2048 /4/256
    hword_kernel<<<80, 256, 0, stream>>>(wf, W2, hw);
    weff_kernel<<<4, 256, 0, stream>>>(W4, W3, we);
    bias_kernel<<<1, 256, 0, stream>>>(b3, W4, b4, bias);
    gemm_himg_kernel<<<196, 256, 0, stream>>>(Xb, W1b, H);
    logits_kernel<<<N_, 256, 0, stream>>>(H, hw, we, bias, lg);
    softmax_kernel<<<B_ * C_, 256, 0, stream>>>(lg, coef);
    fmwc_kernel<<<N_, 256, 0, stream>>>(img, coef, fm);
    semantic_kernel<<<640, 128, 0, stream>>>(img, coef, sem);
}

// Round 3
// 415.861 us; speedup vs baseline: 1.3449x; 1.3449x over previous
//
#include <hip/hip_runtime.h>

typedef __attribute__((ext_vector_type(4))) float float4_t;
typedef __attribute__((ext_vector_type(8))) short short8_t;
typedef __attribute__((ext_vector_type(4))) unsigned short ushort4_t;

#define B_ 8
#define S_ 14
#define P_ 196      // S*S
#define N_ 1568     // B*P
#define D_ 2048
#define C_ 20
#define WD_ 300
#define I_ 1024
#define PS_ 14      // p-splits in semantic partial

__device__ __forceinline__ unsigned short f2bf(float f) {
    unsigned u = __builtin_bit_cast(unsigned, f);
    u += 0x7FFFu + ((u >> 16) & 1u);   // round-to-nearest-even
    return (unsigned short)(u >> 16);
}

// ---------------- fp32 -> bf16 conversion: img (3136 blocks) + W1 (2048 blocks) ----------------
__global__ void cvt_all_kernel(const float* __restrict__ img, const float* __restrict__ W1,
                               unsigned short* __restrict__ Xb, unsigned short* __restrict__ W1b) {
    int bid = blockIdx.x;
    const float* src;
    unsigned short* dst;
    int i4;
    if (bid < 3136) { i4 = bid * 256 + threadIdx.x; src = img; dst = Xb; }
    else            { i4 = (bid - 3136) * 256 + threadIdx.x; src = W1; dst = W1b; }
    float4_t v = ((const float4_t*)src)[i4];
    ushort4_t o;
    o.x = f2bf(v.x); o.y = f2bf(v.y); o.z = f2bf(v.z); o.w = f2bf(v.w);
    ((ushort4_t*)dst)[i4] = o;
}

// ---------------- fused prep: hword (blocks 0..79), weff (80..95), bias (96) ----------------
__global__ __launch_bounds__(256) void prep_kernel(const float* __restrict__ wf,
                                                   const float* __restrict__ W2,
                                                   const float* __restrict__ W3,
                                                   const float* __restrict__ b3,
                                                   const float* __restrict__ W4,
                                                   const float* __restrict__ b4,
                                                   float* __restrict__ hw,
                                                   float* __restrict__ we,
                                                   float* __restrict__ bias) {
    int bid = blockIdx.x, tid = threadIdx.x;
    if (bid < 80) {
        // hw[c,i] = sum_k wf[c,k] * W2[i,k]
        int idx = bid * 256 + tid;
        int c = idx >> 10, i = idx & 1023;
        const float* wr  = wf + c * WD_;
        const float* w2r = W2 + i * WD_;
        float s = 0.f;
        #pragma unroll 4
        for (int k = 0; k < WD_; k++) s += wr[k] * w2r[k];
        hw[idx] = s;
    } else if (bid < 96) {
        // we[i] = sum_j W4[j] * W3[j,i]; 16 blocks x 64 cols, 4-way j split
        __shared__ float red[256];
        int blk = bid - 80;
        int i0 = blk * 64;
        int q = tid >> 6, col = tid & 63;
        float s = 0.f;
        #pragma unroll 4
        for (int j = q * 256; j < q * 256 + 256; j++)
            s += W4[j] * W3[j * I_ + i0 + col];
        red[tid] = s;
        __syncthreads();
        if (tid < 64)
            we[i0 + tid] = red[tid] + red[tid + 64] + red[tid + 128] + red[tid + 192];
    } else {
        // bias = dot(b3, W4) + b4[0]
        __shared__ float r[256];
        float s = 0.f;
        for (int j = tid; j < I_; j += 256) s += b3[j] * W4[j];
        r[tid] = s;
        __syncthreads();
        for (int o = 128; o > 0; o >>= 1) {
            if (tid < o) r[tid] += r[tid + o];
            __syncthreads();
        }
        if (tid == 0) bias[0] = r[0] + b4[0];
    }
}

// ---------------- h_img = X @ W1^T via bf16 MFMA 16x16x32; 32x64 per wave ----------------
__global__ __launch_bounds__(256) void gemm_himg_kernel(const unsigned short* __restrict__ Xb,
                                                        const unsigned short* __restrict__ W1b,
                                                        float* __restrict__ H) {
    int wave = blockIdx.x * 4 + (threadIdx.x >> 6);
    int lane = threadIdx.x & 63;
    int mjob = wave >> 4;       // 0..48
    int njob = wave & 15;       // 0..15
    int m0 = mjob * 32, n0 = njob * 64;
    int ra = lane & 15;
    int kq = (lane >> 4) * 8;

    float4_t acc[2][4] = {};
    const unsigned short* xa = Xb  + (size_t)(m0 + ra) * D_ + kq;
    const unsigned short* wb = W1b + (size_t)(n0 + ra) * D_ + kq;

    #pragma unroll 2
    for (int k0 = 0; k0 < D_; k0 += 32) {
        short8_t a0 = *(const short8_t*)(xa + k0);
        short8_t a1 = *(const short8_t*)(xa + 16 * D_ + k0);
        short8_t b0 = *(const short8_t*)(wb + k0);
        short8_t b1 = *(const short8_t*)(wb + 16 * D_ + k0);
        short8_t b2 = *(const short8_t*)(wb + 32 * D_ + k0);
        short8_t b3v = *(const short8_t*)(wb + 48 * D_ + k0);
        acc[0][0] = __builtin_amdgcn_mfma_f32_16x16x32_bf16(a0, b0, acc[0][0], 0, 0, 0);
        acc[0][1] = __builtin_amdgcn_mfma_f32_16x16x32_bf16(a0, b1, acc[0][1], 0, 0, 0);
        acc[0][2] = __builtin_amdgcn_mfma_f32_16x16x32_bf16(a0, b2, acc[0][2], 0, 0, 0);
        acc[0][3] = __builtin_amdgcn_mfma_f32_16x16x32_bf16(a0, b3v, acc[0][3], 0, 0, 0);
        acc[1][0] = __builtin_amdgcn_mfma_f32_16x16x32_bf16(a1, b0, acc[1][0], 0, 0, 0);
        acc[1][1] = __builtin_amdgcn_mfma_f32_16x16x32_bf16(a1, b1, acc[1][1], 0, 0, 0);
        acc[1][2] = __builtin_amdgcn_mfma_f32_16x16x32_bf16(a1, b2, acc[1][2], 0, 0, 0);
        acc[1][3] = __builtin_amdgcn_mfma_f32_16x16x32_bf16(a1, b3v, acc[1][3], 0, 0, 0);
    }

    int col = lane & 15, rq = (lane >> 4) * 4;
    #pragma unroll
    for (int mt = 0; mt < 2; mt++) {
        #pragma unroll
        for (int nt = 0; nt < 4; nt++) {
            float4_t v = acc[mt][nt];
            int rbase = m0 + mt * 16 + rq;
            int cidx = n0 + nt * 16 + col;
            H[(rbase + 0) * I_ + cidx] = v.x;
            H[(rbase + 1) * I_ + cidx] = v.y;
            H[(rbase + 2) * I_ + cidx] = v.z;
            H[(rbase + 3) * I_ + cidx] = v.w;
        }
    }
}

// ---------------- logits: 4 spatial positions per block ----------------
__global__ __launch_bounds__(256) void logits_kernel(const float* __restrict__ H,
                                                     const float* __restrict__ hw,
                                                     const float* __restrict__ we,
                                                     const float* __restrict__ bias,
                                                     float* __restrict__ lg) {
    __shared__ float sh[4][I_];
    __shared__ float sw[I_];
    int n0 = blockIdx.x * 4, tid = threadIdx.x;
    #pragma unroll
    for (int t = 0; t < 4; t++) {
        int idx = tid + 256 * t;
        sw[idx] = we[idx];
        #pragma unroll
        for (int nn = 0; nn < 4; nn++)
            sh[nn][idx] = H[(size_t)(n0 + nn) * I_ + idx];
    }
    __syncthreads();
    int wv = tid >> 6, lane = tid & 63;
    float bz = bias[0];
    for (int j = 0; j < 5; j++) {
        int c = j * 4 + wv;
        const float* hwc = hw + c * I_;
        float a0 = 0.f, a1 = 0.f, a2 = 0.f, a3 = 0.f;
        #pragma unroll 2
        for (int i = lane; i < I_; i += 64) {
            float hv = hwc[i], wvv = sw[i];
            float x0 = sh[0][i] * hv;
            float x1 = sh[1][i] * hv;
            float x2 = sh[2][i] * hv;
            float x3 = sh[3][i] * hv;
            float t0 = 1.f - __fdividef(2.f, __expf(2.f * x0) + 1.f);
            float t1 = 1.f - __fdividef(2.f, __expf(2.f * x1) + 1.f);
            float t2 = 1.f - __fdividef(2.f, __expf(2.f * x2) + 1.f);
            float t3 = 1.f - __fdividef(2.f, __expf(2.f * x3) + 1.f);
            a0 += t0 * wvv; a1 += t1 * wvv; a2 += t2 * wvv; a3 += t3 * wvv;
        }
        #pragma unroll
        for (int o = 32; o > 0; o >>= 1) {
            a0 += __shfl_down(a0, o);
            a1 += __shfl_down(a1, o);
            a2 += __shfl_down(a2, o);
            a3 += __shfl_down(a3, o);
        }
        if (lane == 0) {
            lg[(n0 + 0) * C_ + c] = a0 + bz;
            lg[(n0 + 1) * C_ + c] = a1 + bz;
            lg[(n0 + 2) * C_ + c] = a2 + bz;
            lg[(n0 + 3) * C_ + c] = a3 + bz;
        }
    }
}

// ---------------- softmax over 196 positions per (b,c); write coef output ----------------
__global__ __launch_bounds__(256) void softmax_kernel(const float* __restrict__ lg,
                                                      float* __restrict__ coef) {
    __shared__ float r[4];
    __shared__ float bval;
    int bx = blockIdx.x;
    int b = bx / C_, c = bx % C_;
    int tid = threadIdx.x, wv = tid >> 6, lane = tid & 63;
    float v = (tid < P_) ? lg[(b * P_ + tid) * C_ + c] : -3.0e38f;
    float m = v;
    #pragma unroll
    for (int o = 32; o > 0; o >>= 1) m = fmaxf(m, __shfl_down(m, o));
    if (lane == 0) r[wv] = m;
    __syncthreads();
    if (tid == 0) bval = fmaxf(fmaxf(r[0], r[1]), fmaxf(r[2], r[3]));
    __syncthreads();
    float mx = bval;
    float e = (tid < P_) ? __expf(v - mx) : 0.f;
    float s = e;
    #pragma unroll
    for (int o = 32; o > 0; o >>= 1) s += __shfl_down(s, o);
    __syncthreads();
    if (lane == 0) r[wv] = s;
    __syncthreads();
    if (tid == 0) bval = r[0] + r[1] + r[2] + r[3];
    __syncthreads();
    if (tid < P_) coef[(b * P_ + tid) * C_ + c] = e / bval;
}

// ---------------- fmwc[b,p,c,d] = img[b,p,d] * coef[b,p,c] ----------------
__global__ __launch_bounds__(256) void fmwc_kernel(const float* __restrict__ img,
                                                   const float* __restrict__ coef,
                                                   float* __restrict__ fm) {
    __shared__ float sc[C_];
    int bp = blockIdx.x, tid = threadIdx.x;
    if (tid < C_) sc[tid] = coef[bp * C_ + tid];
    __syncthreads();
    const float4_t* ir = (const float4_t*)(img + (size_t)bp * D_);
    float4_t v0 = ir[tid], v1 = ir[tid + 256];
    float4_t* ob = (float4_t*)(fm + (size_t)bp * C_ * D_);
    #pragma unroll
    for (int c = 0; c < C_; c++) {
        float s = sc[c];
        ob[c * 512 + tid] = v0 * s;
        ob[c * 512 + tid + 256] = v1 * s;
    }
}

// ---------------- semantic partials: block (ps,b,ch) reads img once, all 20 c in regs ----------------
__global__ __launch_bounds__(256) void semantic_part_kernel(const float* __restrict__ img,
                                                            const float* __restrict__ coef,
                                                            float* __restrict__ part) {
    __shared__ float sc[PS_ * C_];
    int bx = blockIdx.x;
    int ps = bx >> 4;           // 0..13
    int b = (bx >> 1) & 7;
    int ch = bx & 1;
    int tid = threadIdx.x;
    for (int q = tid; q < PS_ * C_; q += 256)           // 280 > 256: strided load (R2 bugfix)
        sc[q] = coef[(b * P_ + ps * PS_) * C_ + q];
    __syncthreads();
    const float4_t* base = (const float4_t*)(img + (size_t)(b * P_ + ps * PS_) * D_ + ch * 1024) + tid;
    float4_t acc[C_];
    #pragma unroll
    for (int c = 0; c < C_; c++) acc[c] = (float4_t){0.f, 0.f, 0.f, 0.f};
    for (int pp = 0; pp < PS_; pp++) {
        float4_t v = base[pp * 512];
        #pragma unroll
        for (int c = 0; c < C_; c++) acc[c] += v * sc[pp * C_ + c];
    }
    float* pb = part + ((size_t)(ps * B_ + b) * C_) * D_ + ch * 1024 + tid * 4;
    #pragma unroll
    for (int c = 0; c < C_; c++) *(float4_t*)(pb + c * D_) = acc[c];
}

// ---------------- semantic reduce over 14 p-splits ----------------
__global__ __launch_bounds__(256) void semantic_reduce_kernel(const float* __restrict__ part,
                                                              float* __restrict__ sem) {
    int idx = blockIdx.x * 256 + threadIdx.x;   // float4 index over B*C*D/4 = 81920
    const float4_t* p4 = (const float4_t*)part;
    float4_t s = {0.f, 0.f, 0.f, 0.f};
    #pragma unroll
    for (int ps = 0; ps < PS_; ps++) s += p4[(size_t)ps * 81920 + idx];
    ((float4_t*)sem)[idx] = s;
}

extern "C" void kernel_launch(void* const* d_in, const int* in_sizes, int n_in,
                              void* d_out, int out_size, void* d_ws, size_t ws_size,
                              hipStream_t stream) {
    const float* img = (const float*)d_in[0];
    const float* wf  = (const float*)d_in[1];
    const float* W1  = (const float*)d_in[2];
    const float* W2  = (const float*)d_in[3];
    const float* W3  = (const float*)d_in[4];
    const float* b3  = (const float*)d_in[5];
    const float* W4  = (const float*)d_in[6];
    const float* b4  = (const float*)d_in[7];

    float* out  = (float*)d_out;
    float* sem  = out;                                  // [B,C,D]      = 327680
    float* fm   = out + (size_t)B_ * C_ * D_;           // [B,S,S,C,D]  = 64225280
    float* coef = fm + (size_t)N_ * C_ * D_;            // [B,S,S,C]    = 31360

    char* ws = (char*)d_ws;
    unsigned short* Xb  = (unsigned short*)ws;                  // 6,422,528 B
    unsigned short* W1b = (unsigned short*)(ws + 6422528);      // 4,194,304 B
    float* H    = (float*)(ws + 10616832);                      // 6,422,528 B
    float* hw   = (float*)(ws + 17039360);                      // 81,920 B
    float* we   = (float*)(ws + 17121280);                      // 4,096 B
    float* bias = (float*)(ws + 17125376);                      // 256 B
    float* lg   = (float*)(ws + 17125632);                      // 125,440 B
    float* part = (float*)(ws + 17251072);                      // 14*8*20*2048*4 = 18,350,080 B

    cvt_all_kernel<<<5184, 256, 0, stream>>>(img, W1, Xb, W1b);
    prep_kernel<<<97, 256, 0, stream>>>(wf, W2, W3, b3, W4, b4, hw, we, bias);
    gemm_himg_kernel<<<196, 256, 0, stream>>>(Xb, W1b, H);
    logits_kernel<<<N_ / 4, 256, 0, stream>>>(H, hw, we, bias, lg);
    softmax_kernel<<<B_ * C_, 256, 0, stream>>>(lg, coef);
    semantic_part_kernel<<<PS_ * B_ * 2, 256, 0, stream>>>(img, coef, part);
    semantic_reduce_kernel<<<320, 256, 0, stream>>>(part, sem);
    fmwc_kernel<<<N_, 256, 0, stream>>>(img, coef, fm);
}